// Round 6
// baseline (2585.286 us; speedup 1.0000x reference)
//
#include <hip/hip_runtime.h>
#include <stdint.h>

#define NB 16
#define HH 128
#define WW 128
#define L (HH*WW)        // 16384
#define CIN 3
#define HID 256
#define NC 21
#define CHUNK 256
#define NCHUNKS (L/CHUNK)   // 64
#define T_PER 32            // t's per wave in k_bp
#define NPACK (L/4)         // 4096 packs of 4 timesteps

// ---------------- K1: conv -> fp32 emissions, TRANSPOSED em_T[b][c][t], LDS input tile ----------------
__global__ __launch_bounds__(256) void k_conv(
    const float* __restrict__ x, const float* __restrict__ w1,
    const float* __restrict__ b1, const float* __restrict__ w2,
    const float* __restrict__ b2, float* __restrict__ emT)
{
    __shared__ float xs[CIN*4*WW];        // 3 ic x 4 rows x 128 cols = 6144 B
    int tid = threadIdx.x;
    int g  = blockIdx.x * 256 + tid;      // 0..B*L-1
    int b  = g >> 14;
    int t0 = (blockIdx.x * 256) & (L-1);  // first t of block (multiple of 256)
    int y0 = t0 >> 7;                     // first of the block's 2 rows
    int dy = tid >> 7;                    // 0 or 1
    int xx = tid & (WW-1);
    int t  = t0 + tid;

    const float* xb = x + (size_t)b * CIN * L;
    for (int i = tid; i < CIN*4*WW; i += 256) {
        int ic  = i >> 9;                 // /512
        int rem = i & 511;
        int rr  = rem >> 7;               // 0..3
        int cc  = rem & 127;
        int row = y0 - 1 + rr;
        xs[i] = (row >= 0 && row < HH) ? xb[ic*L + (row<<7) + cc] : 0.f;
    }
    __syncthreads();

    double p[27];
    #pragma unroll
    for (int ic = 0; ic < CIN; ++ic) {
        #pragma unroll
        for (int ky = 0; ky < 3; ++ky) {
            #pragma unroll
            for (int kx = 0; kx < 3; ++kx) {
                int xc = xx + kx - 1;
                float v = (xc >= 0 && xc < WW) ? xs[ic*512 + (dy+ky)*128 + xc] : 0.f;
                p[ic*9 + ky*3 + kx] = (double)v;
            }
        }
    }

    double acc[NC];
    #pragma unroll
    for (int c = 0; c < NC; ++c) acc[c] = 0.0;

    #pragma unroll 2
    for (int oc = 0; oc < HID; ++oc) {
        double hv = 0.0;                              // conv1 accum
        #pragma unroll
        for (int j = 0; j < 27; ++j) hv += (double)w1[oc*27 + j] * p[j];
        float h32 = (float)hv;                        // round conv1 to fp32
        h32 = h32 + b1[oc];                           // fp32 elementwise bias
        h32 = fmaxf(h32, 0.f);                        // relu (fp32)
        double hd = (double)h32;
        #pragma unroll
        for (int c = 0; c < NC; ++c) acc[c] += (double)w2[c*HID + oc] * hd;
    }
    float* dstb = emT + (size_t)b * NC * L;
    #pragma unroll
    for (int c = 0; c < NC; ++c) {
        float e32 = (float)acc[c];                    // round conv2 to fp32
        dstb[(size_t)c * L + t] = e32 + b2[c];        // transposed store (coalesced in t)
    }
}

// ---------------- K2a: slot-split LDS recursion (plain writes, zero atomic conflicts) ----------------
// s'[n] = fl( max_p fl(s[p]+T[p][n]) + e[n] ) — bitwise equal to ref by RNE monotonicity.
// Ledger (cy/step): R11 9-bperm/2-level=314; R2 11-bperm/1-level=346; R1 readlane=421;
// R3 3-bperm+9crossVALU=551; R5 ds_max/1-level=237 (= ~122 RT + ~42 issue + ~25 VALU + ~48
// CONFLICT: SQ_LDS_BANK_CONFLICT 786384/dispatch = 48 cy/step from 3-way same-address ds_max).
// R6: copy c (lanes 21c..21c+20) computes partial q_c[n] = fl(max_{p in [8c,8c+8)} fl(s[p]+T) + e[n])
// and PLAIN-writes it to slot 3n+c (63 distinct addrs -> <=2/bank = free). Reader computes
// s[p] = max3(triple) — exact; identical candidate set as ref -> sc bit-identical.
// Kills: atomic serialization (-48), init write, readback (reader's max3 pass materializes
// s_{t-1}[p]; a 7-cndmask uniform select extracts s_{t-1}[n] for the lagged sc store).
// DS/step: 6 broadcast ds_read_b128 (3 distinct aligned addrs, conflict-free) + 1 write = 7.
// Pads: slots 63..71 of both buffers = -inf once; tc[p>20] = -inf; -inf + -inf = -inf (no NaN).
// Est ~215 cy/step.
#define NEGINF (-__builtin_huge_valf())

__global__ __launch_bounds__(64) void k_scores(
    const float* __restrict__ emT, const float* __restrict__ start,
    const float* __restrict__ endt, const float* __restrict__ trans,
    float* __restrict__ sc, int* __restrict__ last_tag)
{
    __shared__ float smem[144];            // two 72-float buffers: q triples at 3n+c, pads 63..71
    __shared__ float fin[NC];
    int l = threadIdx.x;
    int b = blockIdx.x;
    int c = l / 21; if (c > 2) c = 2;      // copy 0/1/2; lane 63 dups (2,20) -> identical q, benign
    int n = l - c*21; if (n > 20) n = 20;  // my output state
    int wb  = 8*c;                         // window: p = wb..wb+7
    int wb3 = 24*c;                        // triple-float base of window (16B aligned: 0/96/192 B)
    int wslot = 3*n + c;                   // my write slot
    int ju = n - wb;                       // store index within window
    int j  = ju & 7;
    bool do_store = ((unsigned)ju < 8u) && (l != 63);   // lanes {0-7, 29-36, 58-62} store n

    const float4* er4 = (const float4*)(emT + ((size_t)b * NC + n) * L);
    float*        scp = sc + (size_t)b * NC * L;          // 84 floats per pack

    // 8 transition constants T[wb+i][n]; -inf for p>20 (window pad)
    float tc0, tc1, tc2, tc3, tc4, tc5, tc6, tc7;
    {
        int p0=wb, p1=wb+1, p2=wb+2, p3=wb+3, p4=wb+4, p5=wb+5, p6=wb+6, p7=wb+7;
        tc0 = trans[p0*NC + n];
        tc1 = trans[p1*NC + n];
        tc2 = trans[p2*NC + n];
        tc3 = trans[p3*NC + n];
        tc4 = trans[p4*NC + n];
        tc5 = (p5 < NC) ? trans[p5*NC + n] : NEGINF;
        tc6 = (p6 < NC) ? trans[p6*NC + n] : NEGINF;
        tc7 = (p7 < NC) ? trans[p7*NC + n] : NEGINF;
    }
    asm volatile("" : "+v"(tc0), "+v"(tc1), "+v"(tc2), "+v"(tc3));
    asm volatile("" : "+v"(tc4), "+v"(tc5), "+v"(tc6), "+v"(tc7));

    // STEP(CUR,NXT): reads buf CUR triples (s_{t-1}), writes q to buf NXT (becomes s_t).
    // SEL = s_{t-1}[n] (valid for store lanes), for the lagged sc store.
    #define STEP(CUR, NXT, EV, SEL) { \
        const float* bp_ = &smem[(CUR)*72 + wb3]; \
        float4 r0 = *(const float4*)(bp_+0); \
        float4 r1 = *(const float4*)(bp_+4); \
        float4 r2 = *(const float4*)(bp_+8); \
        float4 r3 = *(const float4*)(bp_+12); \
        float4 r4 = *(const float4*)(bp_+16); \
        float4 r5 = *(const float4*)(bp_+20); \
        float s0 = fmaxf(fmaxf(r0.x, r0.y), r0.z);   /* s[wb+i] = max3(triple) — exact */ \
        float s1 = fmaxf(fmaxf(r0.w, r1.x), r1.y); \
        float s2 = fmaxf(fmaxf(r1.z, r1.w), r2.x); \
        float s3 = fmaxf(fmaxf(r2.y, r2.z), r2.w); \
        float s4 = fmaxf(fmaxf(r3.x, r3.y), r3.z); \
        float s5 = fmaxf(fmaxf(r3.w, r4.x), r4.y); \
        float s6 = fmaxf(fmaxf(r4.z, r4.w), r5.x); \
        float s7 = fmaxf(fmaxf(r5.y, r5.z), r5.w); \
        float x01 = (j&1) ? s1 : s0; \
        float x23 = (j&1) ? s3 : s2; \
        float x45 = (j&1) ? s5 : s4; \
        float x67 = (j&1) ? s7 : s6; \
        float y0  = (j&2) ? x23 : x01; \
        float y1  = (j&2) ? x67 : x45; \
        SEL = (j&4) ? y1 : y0;                       /* s_{t-1}[n] for store lanes */ \
        float w0 = s0+tc0, w1 = s1+tc1, w2 = s2+tc2, w3 = s3+tc3; \
        float w4 = s4+tc4, w5 = s5+tc5, w6 = s6+tc6, w7 = s7+tc7; \
        float m0 = fmaxf(fmaxf(w0,w1),w2); \
        float m1 = fmaxf(fmaxf(w3,w4),w5); \
        float m2 = fmaxf(w6,w7); \
        float q  = fmaxf(fmaxf(m0,m1),m2) + (EV);    /* q_c = fl(pr_c + e[n]) */ \
        smem[(NXT)*72 + wslot] = q; \
    }

    float4 ebuf0 = er4[0];
    float4 ebuf1 = er4[1];

    // ---- t=0 init + pack 0 (t=1..3) ----
    float v0 = ebuf0.x + start[n];         // s0 = fl(em[0]+start), ref order
    smem[wslot] = v0;                      // all 3 copies hold s0[n] -> max3 = s0[n]
    if (l < 9) { smem[63 + l] = NEGINF; smem[135 + l] = NEGINF; }   // pads, both buffers
    float p0 = v0, p1, p2;                 // pending quad (4th arrives via next pack's selA)
    {
        float4 ev = ebuf0;
        ebuf0 = er4[2];
        float selB, selC, selD;
        STEP(0, 1, ev.y, selB)             // t=1 (selB = s0 dup, unused)
        STEP(1, 0, ev.z, selC)             // t=2, selC = s1
        STEP(0, 1, ev.w, selD)             // t=3, selD = s2
        (void)selB;
        p1 = selC; p2 = selD;
    }

    // ---- packs 1..4095; pack k stores pack k-1's quad at its first step ----
    for (int k = 1; k < NPACK; ++k) {
        float4 ev = (k & 1) ? ebuf1 : ebuf0;
        int kp = k + 2; if (kp > NPACK-1) kp = NPACK-1;
        if (k & 1) ebuf1 = er4[kp]; else ebuf0 = er4[kp];

        float selA, selB, selC, selD;
        STEP(1, 0, ev.x, selA)             // t=4k, selA = s_{4k-1}: completes pack k-1
        if (do_store) *(float4*)(scp + (k-1)*84 + n*4) = make_float4(p0, p1, p2, selA);
        STEP(0, 1, ev.y, selB)             // selB = s_{4k}
        STEP(1, 0, ev.z, selC)             // selC = s_{4k+1}
        STEP(0, 1, ev.w, selD)             // selD = s_{4k+2}
        p0 = selB; p1 = selC; p2 = selD;
    }
    #undef STEP

    // ---- final: extract s_{L-1}[n] from buf1 triples (t=16383 is odd -> buf1) ----
    float slast;
    {
        const float* bp_ = &smem[72 + wb3];
        float4 r0 = *(const float4*)(bp_+0);
        float4 r1 = *(const float4*)(bp_+4);
        float4 r2 = *(const float4*)(bp_+8);
        float4 r3 = *(const float4*)(bp_+12);
        float4 r4 = *(const float4*)(bp_+16);
        float4 r5 = *(const float4*)(bp_+20);
        float s0 = fmaxf(fmaxf(r0.x, r0.y), r0.z);
        float s1 = fmaxf(fmaxf(r0.w, r1.x), r1.y);
        float s2 = fmaxf(fmaxf(r1.z, r1.w), r2.x);
        float s3 = fmaxf(fmaxf(r2.y, r2.z), r2.w);
        float s4 = fmaxf(fmaxf(r3.x, r3.y), r3.z);
        float s5 = fmaxf(fmaxf(r3.w, r4.x), r4.y);
        float s6 = fmaxf(fmaxf(r4.z, r4.w), r5.x);
        float s7 = fmaxf(fmaxf(r5.y, r5.z), r5.w);
        float x01 = (j&1) ? s1 : s0;
        float x23 = (j&1) ? s3 : s2;
        float x45 = (j&1) ? s5 : s4;
        float x67 = (j&1) ? s7 : s6;
        float y0  = (j&2) ? x23 : x01;
        float y1  = (j&2) ? x67 : x45;
        slast = (j&4) ? y1 : y0;
    }
    if (do_store) {
        *(float4*)(scp + (NPACK-1)*84 + n*4) = make_float4(p0, p1, p2, slast);
        fin[n] = slast;
    }
    __syncthreads();
    if (l == 0) {
        float bv = fin[0] + endt[0]; int bt = 0;
        #pragma unroll
        for (int jj = 1; jj < NC; ++jj) {
            float v = fin[jj] + endt[jj];
            if (v > bv) { bv = v; bt = jj; }
        }
        last_tag[b] = bt;
    }
}

// ---------------- K2b: parallel backpointer recovery ----------------
// bp[t][n] = first p with fl(fl(s_{t-1}[p]+T[p][n])+e[t][n]) == s_t[n]
__global__ __launch_bounds__(256) void k_bp(
    const float* __restrict__ emT, const float* __restrict__ sc,
    const float* __restrict__ trans, uint8_t* __restrict__ bp)
{
    int wave = threadIdx.x >> 6;
    int lane = threadIdx.x & 63;
    int ne   = lane < NC ? lane : NC-1;

    int bidx  = blockIdx.x;
    int b     = bidx >> 7;                              // 128 blocks per batch
    int tbase = (bidx & 127) * (4*T_PER) + wave*T_PER;

    const float* emb = emT + (size_t)b * NC * L;
    const float* scp = sc  + (size_t)b * NC * L;
    uint8_t*     bpb = bp  + (size_t)b * L * NC;

    float tc[NC];
    #pragma unroll
    for (int pp = 0; pp < NC; ++pp) tc[pp] = trans[pp*NC + ne];

    for (int t = tbase; t < tbase + T_PER; ++t) {
        if (t == 0) continue;
        float target = scp[(t>>2)*84 + ne*4 + (t&3)];
        float e      = emb[(size_t)ne * L + t];
        const float* sp = scp + ((t-1)>>2)*84 + ((t-1)&3);
        int fi = 0;
        #pragma unroll
        for (int pp = NC-1; pp >= 0; --pp) {
            float cand = (sp[pp*4] + tc[pp]) + e;
            if (cand == target) fi = pp;
        }
        if (lane < NC) bpb[(size_t)t * NC + ne] = (uint8_t)fi;
    }
}

// ---------------- K3a: per-chunk jump tables, SEGMENTED chase (exact) ----------------
__global__ __launch_bounds__(64) void k_jump(
    const uint8_t* __restrict__ bp, uint8_t* __restrict__ J)
{
    __shared__ uint32_t lds4[CHUNK*NC/4];    // 5376 B of bp rows [cs..ce)
    __shared__ uint8_t  segJ[8*NC];          // 168 B
    int l   = threadIdx.x;
    int bid = blockIdx.x;
    int b   = bid / (NCHUNKS-1);
    int k   = bid % (NCHUNKS-1) + 1;         // chunks 1..63
    int cs  = k * CHUNK;

    const uint32_t* src = (const uint32_t*)(bp + (size_t)b * L * NC + (size_t)cs * NC);
    for (int i = l; i < CHUNK*NC/4; i += 64) lds4[i] = src[i];
    __syncthreads();
    const uint8_t* lb = (const uint8_t*)lds4;

    // 168 = 8 segs x 21 hyps; chase c -> (s=c/21, h=c%21), rows s*32+31 .. s*32
    int c0 = l, c1 = l + 63, c2 = l + 126;
    bool v2 = (c2 < 8*NC);
    int t0 = c0 % NC, t1 = c1 % NC, t2 = v2 ? (c2 % NC) : 0;
    int r0 = (c0 / NC) * 32, r1 = (c1 / NC) * 32, r2 = v2 ? (c2 / NC) * 32 : 0;
    for (int i = 31; i >= 0; --i) {          // 3 independent chains -> pipelined
        t0 = lb[(r0+i)*NC + t0];
        t1 = lb[(r1+i)*NC + t1];
        if (v2) t2 = lb[(r2+i)*NC + t2];
    }
    segJ[c0] = (uint8_t)t0;
    segJ[c1] = (uint8_t)t1;
    if (v2) segJ[c2] = (uint8_t)t2;
    __syncthreads();

    if (l < NC) {
        int tag = l;
        #pragma unroll
        for (int s = 7; s >= 0; --s) tag = segJ[s*NC + tag];
        J[((size_t)b * NCHUNKS + k) * NC + l] = (uint8_t)tag;
    }
}

// ---------------- K3b: thread chunk entries through jump tables (LDS-staged J) ----------------
__global__ __launch_bounds__(64) void k_seq(
    const uint8_t* __restrict__ J, const int* __restrict__ last_tag,
    uint8_t* __restrict__ ent)
{
    __shared__ uint32_t ldsJ4[NB*NCHUNKS*NC/4];   // 21504 B
    int l = threadIdx.x;
    const uint32_t* src = (const uint32_t*)J;
    for (int i = l; i < NB*NCHUNKS*NC/4; i += 64) ldsJ4[i] = src[i];
    __syncthreads();
    const uint8_t* lj = (const uint8_t*)ldsJ4;

    if (l < NB) {
        int b = l;
        int tag = last_tag[b];                       // tag at t = L-1
        ent[b * NCHUNKS + 63] = (uint8_t)tag;
        for (int k = NCHUNKS-1; k >= 1; --k) {
            tag = lj[((size_t)b * NCHUNKS + k) * NC + tag];
            ent[b * NCHUNKS + (k-1)] = (uint8_t)tag;
        }
    }
}

// ---------------- K3c: per-chunk output, SEGMENTED re-walk from exact seed ----------------
__global__ __launch_bounds__(64) void k_out(
    const uint8_t* __restrict__ bp, const uint8_t* __restrict__ ent,
    int* __restrict__ out)
{
    __shared__ uint32_t lds4[CHUNK*NC/4];
    __shared__ uint8_t  segJ[8*NC];
    __shared__ uint8_t  E[8];
    __shared__ int      tags[CHUNK];
    int l   = threadIdx.x;
    int bid = blockIdx.x;
    int b   = bid >> 6;
    int k   = bid & (NCHUNKS-1);
    int cs  = k * CHUNK;

    const uint32_t* src = (const uint32_t*)(bp + (size_t)b * L * NC + (size_t)cs * NC);
    for (int i = l; i < CHUNK*NC/4; i += 64) lds4[i] = src[i];
    __syncthreads();
    const uint8_t* lb = (const uint8_t*)lds4;

    // phase 2: segment tables (chunk 0 seg 0 crosses t=0: its result is never used)
    int c0 = l, c1 = l + 63, c2 = l + 126;
    bool v2 = (c2 < 8*NC);
    int t0 = c0 % NC, t1 = c1 % NC, t2 = v2 ? (c2 % NC) : 0;
    int r0 = (c0 / NC) * 32, r1 = (c1 / NC) * 32, r2 = v2 ? (c2 / NC) * 32 : 0;
    for (int i = 31; i >= 0; --i) {
        t0 = lb[(r0+i)*NC + t0];
        t1 = lb[(r1+i)*NC + t1];
        if (v2) t2 = lb[(r2+i)*NC + t2];
    }
    segJ[c0] = (uint8_t)(t0 & 31);           // mask: chunk-0/seg-0 garbage stays in-bounds
    segJ[c1] = (uint8_t)(t1 & 31);
    if (v2) segJ[c2] = (uint8_t)(t2 & 31);
    __syncthreads();

    // phase 3: compose segment entry tags E[s] = tag at position cs + 32s + 31
    if (l == 0) {
        int tag = ent[b * NCHUNKS + k];              // exact tag at ce-1
        E[7] = (uint8_t)tag;
        #pragma unroll
        for (int s = 7; s >= 1; --s) { tag = segJ[s*NC + tag]; E[s-1] = (uint8_t)tag; }
    }
    __syncthreads();

    // phase 4: 8 lanes re-walk their 32 rows
    if (l < 8) {
        int tag = E[l];
        int rb  = l * 32;
        for (int i = 31; i >= 0; --i) {              // t = cs+rb+i down to cs+rb
            tags[rb + i] = tag;
            tag = lb[(rb+i)*NC + tag];               // hop at t=0 (chunk 0) unused
        }
    }
    __syncthreads();

    int4* ob = (int4*)(out + (size_t)b * L + cs);
    ob[l] = ((const int4*)tags)[l];                  // 64 lanes x int4 = 256 ints
}

extern "C" void kernel_launch(void* const* d_in, const int* in_sizes, int n_in,
                              void* d_out, int out_size, void* d_ws, size_t ws_size,
                              hipStream_t stream) {
    const float* x  = (const float*)d_in[0];
    const float* w1 = (const float*)d_in[1];
    const float* b1 = (const float*)d_in[2];
    const float* w2 = (const float*)d_in[3];
    const float* b2 = (const float*)d_in[4];
    const float* st = (const float*)d_in[5];
    const float* en = (const float*)d_in[6];
    const float* tr = (const float*)d_in[7];
    int* out = (int*)d_out;

    char* ws = (char*)d_ws;
    float*   em = (float*)ws;                                    // em_T: 22,020,096 B
    float*   sc = (float*)(ws + (size_t)NB*L*NC*4);              // packed scores: 22,020,096 B
    uint8_t* bp = (uint8_t*)(ws + (size_t)NB*L*NC*8);            // 5,505,024 B
    int*     lt = (int*)(ws + (size_t)NB*L*NC*9);                // int[NB]
    // J/ent alias the em region: em is dead after k_bp completes (stream-ordered).
    uint8_t* J   = (uint8_t*)ws;                                 // NB*64*21 = 21,504 B
    uint8_t* ent = (uint8_t*)ws + 21504;                         // NB*64 = 1,024 B

    k_conv  <<<dim3(NB*L/256),       dim3(256), 0, stream>>>(x, w1, b1, w2, b2, em);
    k_scores<<<dim3(NB),             dim3(64),  0, stream>>>(em, st, en, tr, sc, lt);
    k_bp    <<<dim3(NB*128),         dim3(256), 0, stream>>>(em, sc, tr, bp);
    k_jump  <<<dim3(NB*(NCHUNKS-1)), dim3(64),  0, stream>>>(bp, J);
    k_seq   <<<dim3(1),              dim3(64),  0, stream>>>(J, lt, ent);
    k_out   <<<dim3(NB*NCHUNKS),     dim3(64),  0, stream>>>(bp, ent, out);
}

// Round 7
// 1941.332 us; speedup vs baseline: 1.3317x; 1.3317x over previous
//
#include <hip/hip_runtime.h>
#include <stdint.h>

#define NB 16
#define HH 128
#define WW 128
#define L (HH*WW)        // 16384
#define CIN 3
#define HID 256
#define NC 21
#define CHUNK 256
#define NCHUNKS (L/CHUNK)   // 64
#define T_PER 32            // t's per wave in k_bp
#define NPACK (L/4)         // 4096 packs of 4 timesteps

// ---------------- K1: conv -> fp32 emissions, TRANSPOSED em_T[b][c][t], LDS input tile ----------------
__global__ __launch_bounds__(256) void k_conv(
    const float* __restrict__ x, const float* __restrict__ w1,
    const float* __restrict__ b1, const float* __restrict__ w2,
    const float* __restrict__ b2, float* __restrict__ emT)
{
    __shared__ float xs[CIN*4*WW];        // 3 ic x 4 rows x 128 cols = 6144 B
    int tid = threadIdx.x;
    int g  = blockIdx.x * 256 + tid;      // 0..B*L-1
    int b  = g >> 14;
    int t0 = (blockIdx.x * 256) & (L-1);  // first t of block (multiple of 256)
    int y0 = t0 >> 7;                     // first of the block's 2 rows
    int dy = tid >> 7;                    // 0 or 1
    int xx = tid & (WW-1);
    int t  = t0 + tid;

    const float* xb = x + (size_t)b * CIN * L;
    for (int i = tid; i < CIN*4*WW; i += 256) {
        int ic  = i >> 9;                 // /512
        int rem = i & 511;
        int rr  = rem >> 7;               // 0..3
        int cc  = rem & 127;
        int row = y0 - 1 + rr;
        xs[i] = (row >= 0 && row < HH) ? xb[ic*L + (row<<7) + cc] : 0.f;
    }
    __syncthreads();

    double p[27];
    #pragma unroll
    for (int ic = 0; ic < CIN; ++ic) {
        #pragma unroll
        for (int ky = 0; ky < 3; ++ky) {
            #pragma unroll
            for (int kx = 0; kx < 3; ++kx) {
                int xc = xx + kx - 1;
                float v = (xc >= 0 && xc < WW) ? xs[ic*512 + (dy+ky)*128 + xc] : 0.f;
                p[ic*9 + ky*3 + kx] = (double)v;
            }
        }
    }

    double acc[NC];
    #pragma unroll
    for (int c = 0; c < NC; ++c) acc[c] = 0.0;

    #pragma unroll 2
    for (int oc = 0; oc < HID; ++oc) {
        double hv = 0.0;                              // conv1 accum
        #pragma unroll
        for (int j = 0; j < 27; ++j) hv += (double)w1[oc*27 + j] * p[j];
        float h32 = (float)hv;                        // round conv1 to fp32
        h32 = h32 + b1[oc];                           // fp32 elementwise bias
        h32 = fmaxf(h32, 0.f);                        // relu (fp32)
        double hd = (double)h32;
        #pragma unroll
        for (int c = 0; c < NC; ++c) acc[c] += (double)w2[c*HID + oc] * hd;
    }
    float* dstb = emT + (size_t)b * NC * L;
    #pragma unroll
    for (int c = 0; c < NC; ++c) {
        float e32 = (float)acc[c];                    // round conv2 to fp32
        dstb[(size_t)c * L + t] = e32 + b2[c];        // transposed store (coalesced in t)
    }
}

// ---------------- K2a: LDS ds_max recursion, 4 DS ops/step (R5 + wrxchg merge + reads-first) ----
// s'[n] = fl( max_p fl(s[p]+T[p][n]) + e[n] ) — bitwise equal to ref by RNE monotonicity:
// q_c = fl(max_{p in W_c} fl(s[p]+T) + e) = max_{p in W_c} fl(fl(s+T)+e); ds_max over 3 copies
// gives the exact 21-way value. Candidate set identical to ref -> sc bit-identical.
// Ledger (cy/step): R11=314, R2=346, R1=421, R3=551, R5=237 (BEST), R6 slot-split=325.
// R7 deltas vs R5: (a) window b128 reads issued FIRST (R5 issued readback+init ahead of the
// dependent reads, ~16cy on the critical path); (b) readback+init merged into ONE
// ds_wrxchg_rtn_b32 (atomic_exchange(NXT[l], -inf) returns s_{t-2}[l] and initializes) ->
// 5 DS -> 4 DS per step; sc-quad bookkeeping shifts one step later; (c) lane 63's duplicate
// ds_max redirected to a dump slot (state 20: 4-way -> 3-way RMW).
// Ordering: all cross-step pairs (fetch_max -> next reads; reads -> next-next exchange of the
// same buffer) are same-array may-alias (plain vs atomic) -> compiler preserves order; DS pipe
// is in-order per wave (proven by R5). Est ~218-225 cy/step.
#define NEGINF (-__builtin_huge_valf())

__global__ __launch_bounds__(64) void k_scores(
    const float* __restrict__ emT, const float* __restrict__ start,
    const float* __restrict__ endt, const float* __restrict__ trans,
    float* __restrict__ sc, int* __restrict__ last_tag)
{
    __shared__ float smem[128];            // two 64-float ping-pong buffers
    __shared__ float fin[NC];
    int l = threadIdx.x;
    int b = blockIdx.x;
    int c = l / 21; if (c > 2) c = 2;      // copy 0/1/2; lane 63 dups (2,20)
    int n = l - c*21; if (n > 20) n = 20;  // my state
    int wb = 8*c;                          // my p-window: floats [8c .. 8c+7]
    int mslot = (l == 63) ? 63 : n;        // lane63 maxes into dump slot 63 (3-way not 4-way)

    const float4* er4 = (const float4*)(emT + ((size_t)b * NC + n) * L);
    float*        scp = sc + (size_t)b * NC * L;          // 84 floats per pack

    // 8 transition constants T[wb+i][n]; -inf for p>20 (window pad)
    float tc0, tc1, tc2, tc3, tc4, tc5, tc6, tc7;
    {
        int p0=wb, p1=wb+1, p2=wb+2, p3=wb+3, p4=wb+4, p5=wb+5, p6=wb+6, p7=wb+7;
        tc0 = trans[p0*NC + n];
        tc1 = trans[p1*NC + n];
        tc2 = trans[p2*NC + n];
        tc3 = trans[p3*NC + n];
        tc4 = trans[p4*NC + n];
        tc5 = (p5 < NC) ? trans[p5*NC + n] : NEGINF;
        tc6 = (p6 < NC) ? trans[p6*NC + n] : NEGINF;
        tc7 = (p7 < NC) ? trans[p7*NC + n] : NEGINF;
    }
    asm volatile("" : "+v"(tc0), "+v"(tc1), "+v"(tc2), "+v"(tc3));
    asm volatile("" : "+v"(tc4), "+v"(tc5), "+v"(tc6), "+v"(tc7));

    // STEP(CUR,NXT): window reads of CUR (critical, issued first); wrxchg NXT[l] -> RB =
    // s_{t-2}[l] and NXT[l]=-inf (off-path); VALU; ds_max q into NXT[mslot].
    #define STEP(CUR, NXT, EV, RB) { \
        float4 ra  = *(const float4*)&smem[(CUR)*64 + wb]; \
        float4 rb4 = *(const float4*)&smem[(CUR)*64 + wb + 4]; \
        RB = __hip_atomic_exchange(&smem[(NXT)*64 + l], NEGINF, \
                 __ATOMIC_RELAXED, __HIP_MEMORY_SCOPE_WORKGROUP);   /* ds_wrxchg_rtn_b32 */ \
        float w0 = ra.x  + tc0, w1 = ra.y  + tc1, w2 = ra.z  + tc2, w3 = ra.w  + tc3; \
        float w4 = rb4.x + tc4, w5 = rb4.y + tc5, w6 = rb4.z + tc6, w7 = rb4.w + tc7; \
        float m0 = fmaxf(fmaxf(w0, w1), w2); \
        float m1 = fmaxf(fmaxf(w3, w4), w5); \
        float m2 = fmaxf(w6, w7); \
        float q  = fmaxf(fmaxf(m0, m1), m2) + (EV);        /* q_c = fl(pr_c + e[n]) */ \
        (void)__hip_atomic_fetch_max(&smem[(NXT)*64 + mslot], q, \
                 __ATOMIC_RELAXED, __HIP_MEMORY_SCOPE_WORKGROUP);   /* ds_max_f32 */ \
    }

    float4 ebuf0 = er4[0];
    float4 ebuf1 = er4[1];

    // ---- t=0 init + pack 0 (t=1..3) ----
    float v0 = ebuf0.x + start[n];         // s0 = fl(em[0]+start), ref order
    smem[l] = (l < NC) ? v0 : NEGINF;      // buf0 = s0, slots 21..63 = -inf (buf1 init'd by t=1's wrxchg)
    float h0 = v0, h1;                     // two oldest pending quad entries
    {
        float4 ev = ebuf0;
        ebuf0 = er4[2];
        float rb1, rb2, rb3;
        STEP(0, 1, ev.y, rb1)              // t=1: rb1 = garbage (buf1 uninit), discarded
        STEP(1, 0, ev.z, rb2)              // t=2: rb2 = s0 (dup of v0), discarded
        STEP(0, 1, ev.w, rb3)              // t=3: rb3 = s1
        (void)rb1; (void)rb2;
        h1 = rb3;                          // h0 = s0, h1 = s1
    }

    // ---- packs 1..4095; pack k stores pack k-1's quad after its 2nd step ----
    for (int k = 1; k < NPACK; ++k) {
        float4 ev = (k & 1) ? ebuf1 : ebuf0;
        int kp = k + 2; if (kp > NPACK-1) kp = NPACK-1;
        if (k & 1) ebuf1 = er4[kp]; else ebuf0 = er4[kp];

        float rbA, rbB, rbC, rbD;
        STEP(1, 0, ev.x, rbA)              // t=4k:   rbA = s_{4k-2}
        STEP(0, 1, ev.y, rbB)              // t=4k+1: rbB = s_{4k-1}
        if (l < NC) *(float4*)(scp + (k-1)*84 + n*4) = make_float4(h0, h1, rbA, rbB);
        STEP(1, 0, ev.z, rbC)              // t=4k+2: rbC = s_{4k}
        STEP(0, 1, ev.w, rbD)              // t=4k+3: rbD = s_{4k+1}
        h0 = rbC; h1 = rbD;
    }
    #undef STEP

    // ---- epilogue: buf0 = s_{16382}, buf1 = s_{16383} (never exchanged after their writes) ----
    float s2last = smem[l];                // s_{L-2}[n] for l<21
    float s3last = smem[64 + l];           // s_{L-1}[n] for l<21
    if (l < NC) {
        *(float4*)(scp + (NPACK-1)*84 + n*4) = make_float4(h0, h1, s2last, s3last);
        fin[n] = s3last;
    }
    __syncthreads();
    if (l == 0) {
        float bv = fin[0] + endt[0]; int bt = 0;
        #pragma unroll
        for (int j = 1; j < NC; ++j) {
            float v = fin[j] + endt[j];
            if (v > bv) { bv = v; bt = j; }
        }
        last_tag[b] = bt;
    }
}

// ---------------- K2b: parallel backpointer recovery ----------------
// bp[t][n] = first p with fl(fl(s_{t-1}[p]+T[p][n])+e[t][n]) == s_t[n]
__global__ __launch_bounds__(256) void k_bp(
    const float* __restrict__ emT, const float* __restrict__ sc,
    const float* __restrict__ trans, uint8_t* __restrict__ bp)
{
    int wave = threadIdx.x >> 6;
    int lane = threadIdx.x & 63;
    int ne   = lane < NC ? lane : NC-1;

    int bidx  = blockIdx.x;
    int b     = bidx >> 7;                              // 128 blocks per batch
    int tbase = (bidx & 127) * (4*T_PER) + wave*T_PER;

    const float* emb = emT + (size_t)b * NC * L;
    const float* scp = sc  + (size_t)b * NC * L;
    uint8_t*     bpb = bp  + (size_t)b * L * NC;

    float tc[NC];
    #pragma unroll
    for (int pp = 0; pp < NC; ++pp) tc[pp] = trans[pp*NC + ne];

    for (int t = tbase; t < tbase + T_PER; ++t) {
        if (t == 0) continue;
        float target = scp[(t>>2)*84 + ne*4 + (t&3)];
        float e      = emb[(size_t)ne * L + t];
        const float* sp = scp + ((t-1)>>2)*84 + ((t-1)&3);
        int fi = 0;
        #pragma unroll
        for (int pp = NC-1; pp >= 0; --pp) {
            float cand = (sp[pp*4] + tc[pp]) + e;
            if (cand == target) fi = pp;
        }
        if (lane < NC) bpb[(size_t)t * NC + ne] = (uint8_t)fi;
    }
}

// ---------------- K3a: per-chunk jump tables, SEGMENTED chase (exact) ----------------
__global__ __launch_bounds__(64) void k_jump(
    const uint8_t* __restrict__ bp, uint8_t* __restrict__ J)
{
    __shared__ uint32_t lds4[CHUNK*NC/4];    // 5376 B of bp rows [cs..ce)
    __shared__ uint8_t  segJ[8*NC];          // 168 B
    int l   = threadIdx.x;
    int bid = blockIdx.x;
    int b   = bid / (NCHUNKS-1);
    int k   = bid % (NCHUNKS-1) + 1;         // chunks 1..63
    int cs  = k * CHUNK;

    const uint32_t* src = (const uint32_t*)(bp + (size_t)b * L * NC + (size_t)cs * NC);
    for (int i = l; i < CHUNK*NC/4; i += 64) lds4[i] = src[i];
    __syncthreads();
    const uint8_t* lb = (const uint8_t*)lds4;

    // 168 = 8 segs x 21 hyps; chase c -> (s=c/21, h=c%21), rows s*32+31 .. s*32
    int c0 = l, c1 = l + 63, c2 = l + 126;
    bool v2 = (c2 < 8*NC);
    int t0 = c0 % NC, t1 = c1 % NC, t2 = v2 ? (c2 % NC) : 0;
    int r0 = (c0 / NC) * 32, r1 = (c1 / NC) * 32, r2 = v2 ? (c2 / NC) * 32 : 0;
    for (int i = 31; i >= 0; --i) {          // 3 independent chains -> pipelined
        t0 = lb[(r0+i)*NC + t0];
        t1 = lb[(r1+i)*NC + t1];
        if (v2) t2 = lb[(r2+i)*NC + t2];
    }
    segJ[c0] = (uint8_t)t0;
    segJ[c1] = (uint8_t)t1;
    if (v2) segJ[c2] = (uint8_t)t2;
    __syncthreads();

    if (l < NC) {
        int tag = l;
        #pragma unroll
        for (int s = 7; s >= 0; --s) tag = segJ[s*NC + tag];
        J[((size_t)b * NCHUNKS + k) * NC + l] = (uint8_t)tag;
    }
}

// ---------------- K3b: thread chunk entries through jump tables (LDS-staged J) ----------------
__global__ __launch_bounds__(64) void k_seq(
    const uint8_t* __restrict__ J, const int* __restrict__ last_tag,
    uint8_t* __restrict__ ent)
{
    __shared__ uint32_t ldsJ4[NB*NCHUNKS*NC/4];   // 21504 B
    int l = threadIdx.x;
    const uint32_t* src = (const uint32_t*)J;
    for (int i = l; i < NB*NCHUNKS*NC/4; i += 64) ldsJ4[i] = src[i];
    __syncthreads();
    const uint8_t* lj = (const uint8_t*)ldsJ4;

    if (l < NB) {
        int b = l;
        int tag = last_tag[b];                       // tag at t = L-1
        ent[b * NCHUNKS + 63] = (uint8_t)tag;
        for (int k = NCHUNKS-1; k >= 1; --k) {
            tag = lj[((size_t)b * NCHUNKS + k) * NC + tag];
            ent[b * NCHUNKS + (k-1)] = (uint8_t)tag;
        }
    }
}

// ---------------- K3c: per-chunk output, SEGMENTED re-walk from exact seed ----------------
__global__ __launch_bounds__(64) void k_out(
    const uint8_t* __restrict__ bp, const uint8_t* __restrict__ ent,
    int* __restrict__ out)
{
    __shared__ uint32_t lds4[CHUNK*NC/4];
    __shared__ uint8_t  segJ[8*NC];
    __shared__ uint8_t  E[8];
    __shared__ int      tags[CHUNK];
    int l   = threadIdx.x;
    int bid = blockIdx.x;
    int b   = bid >> 6;
    int k   = bid & (NCHUNKS-1);
    int cs  = k * CHUNK;

    const uint32_t* src = (const uint32_t*)(bp + (size_t)b * L * NC + (size_t)cs * NC);
    for (int i = l; i < CHUNK*NC/4; i += 64) lds4[i] = src[i];
    __syncthreads();
    const uint8_t* lb = (const uint8_t*)lds4;

    // phase 2: segment tables (chunk 0 seg 0 crosses t=0: its result is never used)
    int c0 = l, c1 = l + 63, c2 = l + 126;
    bool v2 = (c2 < 8*NC);
    int t0 = c0 % NC, t1 = c1 % NC, t2 = v2 ? (c2 % NC) : 0;
    int r0 = (c0 / NC) * 32, r1 = (c1 / NC) * 32, r2 = v2 ? (c2 / NC) * 32 : 0;
    for (int i = 31; i >= 0; --i) {
        t0 = lb[(r0+i)*NC + t0];
        t1 = lb[(r1+i)*NC + t1];
        if (v2) t2 = lb[(r2+i)*NC + t2];
    }
    segJ[c0] = (uint8_t)(t0 & 31);           // mask: chunk-0/seg-0 garbage stays in-bounds
    segJ[c1] = (uint8_t)(t1 & 31);
    if (v2) segJ[c2] = (uint8_t)(t2 & 31);
    __syncthreads();

    // phase 3: compose segment entry tags E[s] = tag at position cs + 32s + 31
    if (l == 0) {
        int tag = ent[b * NCHUNKS + k];              // exact tag at ce-1
        E[7] = (uint8_t)tag;
        #pragma unroll
        for (int s = 7; s >= 1; --s) { tag = segJ[s*NC + tag]; E[s-1] = (uint8_t)tag; }
    }
    __syncthreads();

    // phase 4: 8 lanes re-walk their 32 rows
    if (l < 8) {
        int tag = E[l];
        int rb  = l * 32;
        for (int i = 31; i >= 0; --i) {              // t = cs+rb+i down to cs+rb
            tags[rb + i] = tag;
            tag = lb[(rb+i)*NC + tag];               // hop at t=0 (chunk 0) unused
        }
    }
    __syncthreads();

    int4* ob = (int4*)(out + (size_t)b * L + cs);
    ob[l] = ((const int4*)tags)[l];                  // 64 lanes x int4 = 256 ints
}

extern "C" void kernel_launch(void* const* d_in, const int* in_sizes, int n_in,
                              void* d_out, int out_size, void* d_ws, size_t ws_size,
                              hipStream_t stream) {
    const float* x  = (const float*)d_in[0];
    const float* w1 = (const float*)d_in[1];
    const float* b1 = (const float*)d_in[2];
    const float* w2 = (const float*)d_in[3];
    const float* b2 = (const float*)d_in[4];
    const float* st = (const float*)d_in[5];
    const float* en = (const float*)d_in[6];
    const float* tr = (const float*)d_in[7];
    int* out = (int*)d_out;

    char* ws = (char*)d_ws;
    float*   em = (float*)ws;                                    // em_T: 22,020,096 B
    float*   sc = (float*)(ws + (size_t)NB*L*NC*4);              // packed scores: 22,020,096 B
    uint8_t* bp = (uint8_t*)(ws + (size_t)NB*L*NC*8);            // 5,505,024 B
    int*     lt = (int*)(ws + (size_t)NB*L*NC*9);                // int[NB]
    // J/ent alias the em region: em is dead after k_bp completes (stream-ordered).
    uint8_t* J   = (uint8_t*)ws;                                 // NB*64*21 = 21,504 B
    uint8_t* ent = (uint8_t*)ws + 21504;                         // NB*64 = 1,024 B

    k_conv  <<<dim3(NB*L/256),       dim3(256), 0, stream>>>(x, w1, b1, w2, b2, em);
    k_scores<<<dim3(NB),             dim3(64),  0, stream>>>(em, st, en, tr, sc, lt);
    k_bp    <<<dim3(NB*128),         dim3(256), 0, stream>>>(em, sc, tr, bp);
    k_jump  <<<dim3(NB*(NCHUNKS-1)), dim3(64),  0, stream>>>(bp, J);
    k_seq   <<<dim3(1),              dim3(64),  0, stream>>>(J, lt, ent);
    k_out   <<<dim3(NB*NCHUNKS),     dim3(64),  0, stream>>>(bp, ent, out);
}